// Round 1
// baseline (164.172 us; speedup 1.0000x reference)
//
#include <hip/hip_runtime.h>
#include <hip/hip_bf16.h>

#define NQ 10000
#define BATCH 64
#define SEQL 200
#define DKD 128
#define SLOTS 64
#define NTOK (BATCH*SEQL)

__device__ __forceinline__ float sigmoidf_(float x){ return 1.0f/(1.0f + __expf(-x)); }
__device__ __forceinline__ float tanhf_(float x){
  float ax = fminf(fabsf(x), 30.0f);
  float t = __expf(-2.0f*ax);
  float r = (1.0f-t)/(1.0f+t);
  return copysignf(r, x);
}

// ---------------- Phase 1: w = softmax(k Mk^T), e = sigmoid(v eW^T), a = tanh(v aW^T) ----------------
// 256 thr = 4 waves. il = wave id (0..3), g = lane (0..63).
// 32 tokens/block. Thread computes 8 tokens (il+4j) x 1 output row (g) per stage.
// Weight row (128 floats) lives in 32 float4 REGISTERS; token reads are wave-broadcast LDS.
__global__ __launch_bounds__(256) void phase1_kernel(
    const int* __restrict__ qseq, const int* __restrict__ cseq,
    const float* __restrict__ q_emb, const float* __restrict__ v_emb,
    const float* __restrict__ Mk, const float* __restrict__ eW,
    const float* __restrict__ eb, const float* __restrict__ aW,
    const float* __restrict__ ab,
    float* __restrict__ w_out, float* __restrict__ e_out, float* __restrict__ a_out)
{
  __shared__ float ks[32][132];
  __shared__ float vs[32][132];
  __shared__ float wsb[64*132];
  const int tid = threadIdx.x;
  const int il = tid >> 6;   // wave id 0..3
  const int g  = tid & 63;   // lane
  const int tok0 = blockIdx.x * 32;

  { // gather k, v into LDS (coalesced float4)
    int i = tid >> 3, jb = tid & 7;
    int q = qseq[tok0 + i];
    int c = cseq[tok0 + i];
    const float4* kr = (const float4*)(q_emb + (size_t)q * DKD);
    const float4* vr = (const float4*)(v_emb + (size_t)(q + NQ*c) * DKD);
    #pragma unroll
    for (int m = 0; m < 4; ++m){
      int j = jb + 8*m;
      *(float4*)&ks[i][j*4] = kr[j];
      *(float4*)&vs[i][j*4] = vr[j];
    }
  }
  { // stage 0 weights (Mk, 64x128) global->LDS, coalesced
    const float4* s4 = (const float4*)Mk;
    #pragma unroll
    for (int m = 0; m < 8; ++m){
      int idx = tid + 256*m;
      *(float4*)&wsb[(idx>>5)*132 + (idx&31)*4] = s4[idx];
    }
  }

  float4 wr[32];
  for (int s = 0; s < 5; ++s){
    __syncthreads();                       // wsb[s] ready
    #pragma unroll
    for (int c4 = 0; c4 < 32; ++c4) wr[c4] = *(const float4*)&wsb[g*132 + c4*4];
    __syncthreads();                       // everyone copied; wsb free
    if (s < 4){                            // issue next stage's loads (latency hides under FMA)
      const float* src = (s==0)? eW : (s==1)? (eW + 64*DKD) : (s==2)? aW : (aW + 64*DKD);
      const float4* s4 = (const float4*)src;
      #pragma unroll
      for (int m = 0; m < 8; ++m){
        int idx = tid + 256*m;
        *(float4*)&wsb[(idx>>5)*132 + (idx&31)*4] = s4[idx];
      }
    }
    const float (*TS)[132] = (s==0) ? ks : vs;
    float acc[8] = {0.f,0.f,0.f,0.f,0.f,0.f,0.f,0.f};
    #pragma unroll
    for (int c4 = 0; c4 < 32; ++c4){
      float4 w = wr[c4];
      #pragma unroll
      for (int j = 0; j < 8; ++j){
        float4 x = *(const float4*)&TS[il + 4*j][c4*4];
        acc[j] = fmaf(x.x, w.x, acc[j]);
        acc[j] = fmaf(x.y, w.y, acc[j]);
        acc[j] = fmaf(x.z, w.z, acc[j]);
        acc[j] = fmaf(x.w, w.w, acc[j]);
      }
    }
    if (s == 0){
      // softmax over 64 slots == the 64 lanes of this wave
      #pragma unroll
      for (int j = 0; j < 8; ++j){
        float mx = acc[j];
        #pragma unroll
        for (int off = 32; off >= 1; off >>= 1) mx = fmaxf(mx, __shfl_xor(mx, off));
        float pe = __expf(acc[j] - mx);
        float sm = pe;
        #pragma unroll
        for (int off = 32; off >= 1; off >>= 1) sm += __shfl_xor(sm, off);
        w_out[(size_t)(tok0 + il + 4*j)*SLOTS + g] = pe / sm;
      }
    } else {
      const bool is_e = (s <= 2);
      const int d = ((s-1)&1)*64 + g;
      const float bias = (is_e ? eb : ab)[d];
      float* obuf = is_e ? e_out : a_out;
      #pragma unroll
      for (int j = 0; j < 8; ++j){
        float xv = acc[j] + bias;
        obuf[(size_t)(tok0 + il + 4*j)*DKD + d] = is_e ? sigmoidf_(xv) : tanhf_(xv);
      }
    }
  }
}

// ---------------- Phase 2: sequential scan over t; independent per (b,d); s split over 16 lanes ----
__global__ __launch_bounds__(256) void scan_kernel(
    const float* __restrict__ Mv0,
    const float* __restrict__ w_in, const float* __restrict__ e_in,
    const float* __restrict__ a_in, float* __restrict__ r_out)
{
  const int gid = blockIdx.x*256 + threadIdx.x;
  const int g = gid & 15;           // s-group: owns s = 4g..4g+3
  const int p = gid >> 4;           // (b,d) pair 0..8191
  const int b = p >> 7;
  const int d = p & 127;
  float mv[4];
  #pragma unroll
  for (int i = 0; i < 4; ++i) mv[i] = Mv0[(4*g + i)*DKD + d];
  const float4* w4 = ((const float4*)(w_in + (size_t)b*SEQL*SLOTS)) + g;  // +t*16 per step
  const float*  ep = e_in + (size_t)b*SEQL*DKD + d;
  const float*  ap = a_in + (size_t)b*SEQL*DKD + d;
  float*        rp = r_out + (size_t)b*SEQL*DKD + d;

  float4 wv = w4[0];
  float  ev = ep[0], av = ap[0];
  for (int t = 0; t < SEQL; ++t){
    const int tn = (t < SEQL-1) ? t+1 : t;      // branchless OOB guard
    float4 wvn = w4[(size_t)tn*16];             // prefetch next step
    float  evn = ep[(size_t)tn*DKD];
    float  avn = ap[(size_t)tn*DKD];
    // read_t[d] partial over my 4 slots, then 16-lane xor-reduce
    float r0 = fmaf(wv.x, mv[0], wv.y*mv[1]);
    float r1 = fmaf(wv.z, mv[2], wv.w*mv[3]);
    float r = r0 + r1;
    r += __shfl_xor(r, 1);
    r += __shfl_xor(r, 2);
    r += __shfl_xor(r, 4);
    r += __shfl_xor(r, 8);
    if (g == 0) rp[(size_t)t*DKD] = r;
    // Mv <- Mv + w*(a - Mv*e)
    mv[0] = fmaf(wv.x, fmaf(-mv[0], ev, av), mv[0]);
    mv[1] = fmaf(wv.y, fmaf(-mv[1], ev, av), mv[1]);
    mv[2] = fmaf(wv.z, fmaf(-mv[2], ev, av), mv[2]);
    mv[3] = fmaf(wv.w, fmaf(-mv[3], ev, av), mv[3]);
    wv = wvn; ev = evn; av = avn;
  }
}

// ---------------- Phase 3: f = tanh([read,k] fW^T + fb); out = sigmoid(f pW^T + pb) (f stays in regs)
__global__ __launch_bounds__(256) void phase3_kernel(
    const int* __restrict__ qseq, const float* __restrict__ q_emb,
    const float* __restrict__ r_in, const float* __restrict__ fW,
    const float* __restrict__ fb, const float* __restrict__ pW,
    const float* __restrict__ pb, float* __restrict__ out)
{
  __shared__ float ins[32][260];     // cols 0..127 = read, 128..255 = k
  __shared__ float wsb[64*132];
  const int tid = threadIdx.x;
  const int il = tid >> 6, g = tid & 63;
  const int tok0 = blockIdx.x * 32;

  #pragma unroll
  for (int m = 0; m < 8; ++m){       // gather [read | k] tile
    int idx = tid + 256*m;           // 0..2047 over 32 tok x 64 f4
    int i = idx >> 6, c4 = idx & 63;
    float4 v;
    if (c4 < 32) v = ((const float4*)r_in)[(size_t)(tok0 + i)*32 + c4];
    else {
      int q = qseq[tok0 + i];
      v = ((const float4*)q_emb)[(size_t)q*32 + (c4 - 32)];
    }
    *(float4*)&ins[i][c4*4] = v;
  }
  { // stage 0: dstage 0, khalf 0
    const float4* f4p = (const float4*)fW;
    #pragma unroll
    for (int m = 0; m < 8; ++m){
      int idx = tid + 256*m;
      int row = idx >> 5, c4 = idx & 31;
      *(float4*)&wsb[row*132 + c4*4] = f4p[(size_t)row*64 + c4];
    }
  }

  float4 wr[32];
  float acc[8];
  float pacc[8] = {0.f,0.f,0.f,0.f,0.f,0.f,0.f,0.f};
  for (int s = 0; s < 4; ++s){       // s = dstage*2 + khalf
    const int dstage = s >> 1, khalf = s & 1;
    __syncthreads();
    #pragma unroll
    for (int c4 = 0; c4 < 32; ++c4) wr[c4] = *(const float4*)&wsb[g*132 + c4*4];
    __syncthreads();
    if (s < 3){
      const int ds2 = (s+1) >> 1, kh2 = (s+1) & 1;
      const float4* f4p = (const float4*)fW;
      #pragma unroll
      for (int m = 0; m < 8; ++m){
        int idx = tid + 256*m;
        int row = idx >> 5, c4 = idx & 31;
        *(float4*)&wsb[row*132 + c4*4] = f4p[(size_t)(ds2*64 + row)*64 + kh2*32 + c4];
      }
    }
    if (khalf == 0){
      #pragma unroll
      for (int j = 0; j < 8; ++j) acc[j] = 0.f;
    }
    #pragma unroll
    for (int c4 = 0; c4 < 32; ++c4){
      float4 w = wr[c4];
      #pragma unroll
      for (int j = 0; j < 8; ++j){
        float4 x = *(const float4*)&ins[il + 4*j][khalf*128 + c4*4];
        acc[j] = fmaf(x.x, w.x, acc[j]);
        acc[j] = fmaf(x.y, w.y, acc[j]);
        acc[j] = fmaf(x.z, w.z, acc[j]);
        acc[j] = fmaf(x.w, w.w, acc[j]);
      }
    }
    if (khalf == 1){
      const int dd = dstage*64 + g;
      const float bias = fb[dd], pw = pW[dd];
      #pragma unroll
      for (int j = 0; j < 8; ++j){
        float f = tanhf_(acc[j] + bias);
        pacc[j] = fmaf(f, pw, pacc[j]);
      }
    }
  }
  const float pbv = pb[0];
  #pragma unroll
  for (int j = 0; j < 8; ++j){
    float pv = pacc[j];
    #pragma unroll
    for (int off = 32; off >= 1; off >>= 1) pv += __shfl_xor(pv, off);
    if (g == 0) out[tok0 + il + 4*j] = sigmoidf_(pv + pbv);
  }
}

extern "C" void kernel_launch(void* const* d_in, const int* in_sizes, int n_in,
                              void* d_out, int out_size, void* d_ws, size_t ws_size,
                              hipStream_t stream) {
  const int*   qseq  = (const int*)d_in[0];
  const int*   cseq  = (const int*)d_in[1];
  const float* q_emb = (const float*)d_in[2];
  const float* v_emb = (const float*)d_in[3];
  const float* Mk    = (const float*)d_in[4];
  const float* Mv0   = (const float*)d_in[5];
  const float* eW    = (const float*)d_in[6];
  const float* eb    = (const float*)d_in[7];
  const float* aW    = (const float*)d_in[8];
  const float* ab    = (const float*)d_in[9];
  const float* fW    = (const float*)d_in[10];
  const float* fb    = (const float*)d_in[11];
  const float* pW    = (const float*)d_in[12];
  const float* pb    = (const float*)d_in[13];

  float* w_buf = (float*)d_ws;                       // 12800*64
  float* e_buf = w_buf + (size_t)NTOK*SLOTS;         // 12800*128
  float* a_buf = e_buf + (size_t)NTOK*DKD;           // 12800*128
  float* r_buf = a_buf + (size_t)NTOK*DKD;           // 12800*128
  float* outp  = (float*)d_out;

  hipLaunchKernelGGL(phase1_kernel, dim3(NTOK/32), dim3(256), 0, stream,
                     qseq, cseq, q_emb, v_emb, Mk, eW, eb, aW, ab, w_buf, e_buf, a_buf);
  hipLaunchKernelGGL(scan_kernel, dim3((BATCH*DKD*16)/256), dim3(256), 0, stream,
                     Mv0, w_buf, e_buf, a_buf, r_buf);
  hipLaunchKernelGGL(phase3_kernel, dim3(NTOK/32), dim3(256), 0, stream,
                     qseq, q_emb, r_buf, fW, fb, pW, pb, outp);
}

// Round 2
// 104.614 us; speedup vs baseline: 1.5693x; 1.5693x over previous
//
#include <hip/hip_runtime.h>
#include <hip/hip_bf16.h>

#define NQ 10000
#define BATCH 64
#define SEQL 200
#define DKD 128
#define SLOTS 64
#define NTOK (BATCH*SEQL)

__device__ __forceinline__ float sigmoidf_(float x){ return 1.0f/(1.0f + __expf(-x)); }
__device__ __forceinline__ float tanhf_(float x){
  float ax = fminf(fabsf(x), 30.0f);
  float t = __expf(-2.0f*ax);
  float r = (1.0f-t)/(1.0f+t);
  return copysignf(r, x);
}

// ---------------- Kernel W: w = softmax(k Mk^T) ----------------
// 400 blocks x 256 thr. Tile 32 tok x 64 slots. micro 4 tok x 2 slots.
__global__ __launch_bounds__(256) void w_kernel(
    const int* __restrict__ qseq, const float* __restrict__ q_emb,
    const float* __restrict__ Mk, float* __restrict__ w_out)
{
  __shared__ float A[32][132];     // k rows (pad)
  __shared__ float B[64*128];      // Mk swizzled: word = out*128 + (k4 ^ ((out>>2)&15))*4
  const int tid = threadIdx.x;
  const int tx = tid & 31, ty = tid >> 5;
  const int tok0 = blockIdx.x * 32;

  #pragma unroll
  for (int m = 0; m < 4; ++m){     // stage A: 1024 f4
    int idx = tid + 256*m;
    int row = idx >> 5, c4 = idx & 31;
    int q = qseq[tok0 + row];
    *(float4*)&A[row][c4*4] = ((const float4*)q_emb)[(size_t)q*32 + c4];
  }
  #pragma unroll
  for (int m = 0; m < 8; ++m){     // stage B: 2048 f4 swizzled
    int idx = tid + 256*m;
    int out = idx >> 5, k4 = idx & 31;
    int s = k4 ^ ((out >> 2) & 15);
    *(float4*)&B[out*128 + s*4] = ((const float4*)Mk)[(size_t)out*32 + k4];
  }
  __syncthreads();

  float acc[4][2] = {};
  const int xb = (tx >> 2) & 7;
  #pragma unroll
  for (int kk = 0; kk < 32; ++kk){
    float4 rA[4], rB[2];
    #pragma unroll
    for (int i = 0; i < 4; ++i) rA[i] = *(const float4*)&A[ty*4+i][kk*4];
    rB[0] = *(const float4*)&B[tx*128 + ((kk ^ xb) & 31)*4];
    rB[1] = *(const float4*)&B[(tx+32)*128 + ((kk ^ xb ^ 8) & 31)*4];
    #pragma unroll
    for (int j = 0; j < 2; ++j){
      #pragma unroll
      for (int i = 0; i < 4; ++i){
        acc[i][j] = fmaf(rA[i].x, rB[j].x, acc[i][j]);
        acc[i][j] = fmaf(rA[i].y, rB[j].y, acc[i][j]);
        acc[i][j] = fmaf(rA[i].z, rB[j].z, acc[i][j]);
        acc[i][j] = fmaf(rA[i].w, rB[j].w, acc[i][j]);
      }
    }
  }
  #pragma unroll
  for (int i = 0; i < 4; ++i){
    float m = fmaxf(acc[i][0], acc[i][1]);
    #pragma unroll
    for (int off = 16; off >= 1; off >>= 1) m = fmaxf(m, __shfl_xor(m, off));
    float p0 = __expf(acc[i][0] - m), p1 = __expf(acc[i][1] - m);
    float s = p0 + p1;
    #pragma unroll
    for (int off = 16; off >= 1; off >>= 1) s += __shfl_xor(s, off);
    float rs = 1.0f / s;
    int tok = tok0 + ty*4 + i;
    w_out[(size_t)tok*SLOTS + tx]      = p0 * rs;
    w_out[(size_t)tok*SLOTS + tx + 32] = p1 * rs;
  }
}

// ---------------- Kernel EA: e = sigmoid(v eW^T), a = tanh(v aW^T) ----------------
// 400 blocks. Tile 32 tok x 256 out (e||a). micro 4 tok x 8 out. K quartered (32).
__global__ __launch_bounds__(256) void ea_kernel(
    const int* __restrict__ qseq, const int* __restrict__ cseq,
    const float* __restrict__ v_emb,
    const float* __restrict__ eW, const float* __restrict__ eb,
    const float* __restrict__ aW, const float* __restrict__ ab,
    float* __restrict__ e_out, float* __restrict__ a_out)
{
  __shared__ float A[32][36];      // v rows, one k-quarter
  __shared__ float B[256*32];      // 256 out x 32 k swizzled
  __shared__ int xids[32];
  const int tid = threadIdx.x;
  const int tx = tid & 31, ty = tid >> 5;
  const int tok0 = blockIdx.x * 32;
  if (tid < 32) xids[tid] = qseq[tok0+tid] + NQ*cseq[tok0+tid];

  float acc[4][8] = {};
  const int xb = (tx >> 2) & 7;
  for (int q = 0; q < 4; ++q){
    __syncthreads();               // xids ready (q=0) / prev compute done (q>0)
    { int row = tid >> 3, c4 = tid & 7;
      *(float4*)&A[row][c4*4] = ((const float4*)v_emb)[(size_t)xids[row]*32 + q*8 + c4]; }
    #pragma unroll
    for (int m = 0; m < 8; ++m){
      int idx = tid + 256*m;
      int out = idx >> 3, k4 = idx & 7;
      const float* Wp = (out < 128) ? eW : aW;
      int orow = out & 127;
      int s = k4 ^ ((out >> 2) & 7);
      *(float4*)&B[out*32 + s*4] = ((const float4*)Wp)[(size_t)orow*32 + q*8 + k4];
    }
    __syncthreads();
    #pragma unroll
    for (int kk = 0; kk < 8; ++kk){
      float4 rA[4];
      #pragma unroll
      for (int i = 0; i < 4; ++i) rA[i] = *(const float4*)&A[ty*4+i][kk*4];
      #pragma unroll
      for (int j = 0; j < 8; ++j){
        float4 rB = *(const float4*)&B[(tx+32*j)*32 + ((kk ^ xb) & 7)*4];
        #pragma unroll
        for (int i = 0; i < 4; ++i){
          acc[i][j] = fmaf(rA[i].x, rB.x, acc[i][j]);
          acc[i][j] = fmaf(rA[i].y, rB.y, acc[i][j]);
          acc[i][j] = fmaf(rA[i].z, rB.z, acc[i][j]);
          acc[i][j] = fmaf(rA[i].w, rB.w, acc[i][j]);
        }
      }
    }
  }
  #pragma unroll
  for (int j = 0; j < 8; ++j){
    int out = tx + 32*j;
    bool is_e = (out < 128);
    int d = out & 127;
    float bias = is_e ? eb[d] : ab[d];
    float* obuf = is_e ? e_out : a_out;
    #pragma unroll
    for (int i = 0; i < 4; ++i){
      int tok = tok0 + ty*4 + i;
      float xv = acc[i][j] + bias;
      obuf[(size_t)tok*DKD + d] = is_e ? sigmoidf_(xv) : tanhf_(xv);
    }
  }
}

// ---------------- Scan: DPP row-sum reduce + distance-8 prefetch ----------------
__device__ __forceinline__ float dpp_row_sum16(float x){
  float t;
  t = __builtin_bit_cast(float, __builtin_amdgcn_update_dpp(0, __builtin_bit_cast(int,x), 0x111, 0xf, 0xf, true)); x += t; // row_shr:1
  t = __builtin_bit_cast(float, __builtin_amdgcn_update_dpp(0, __builtin_bit_cast(int,x), 0x112, 0xf, 0xf, true)); x += t; // row_shr:2
  t = __builtin_bit_cast(float, __builtin_amdgcn_update_dpp(0, __builtin_bit_cast(int,x), 0x114, 0xf, 0xf, true)); x += t; // row_shr:4
  t = __builtin_bit_cast(float, __builtin_amdgcn_update_dpp(0, __builtin_bit_cast(int,x), 0x118, 0xf, 0xf, true)); x += t; // row_shr:8
  return x;  // lane 15 (mod 16) holds the 16-lane sum
}

__global__ __launch_bounds__(256) void scan_kernel(
    const float* __restrict__ Mv0,
    const float* __restrict__ w_in, const float* __restrict__ e_in,
    const float* __restrict__ a_in, float* __restrict__ r_out)
{
  const int gid = blockIdx.x*256 + threadIdx.x;
  const int g = gid & 15;           // owns slots 4g..4g+3
  const int p = gid >> 4;           // (b,d)
  const int b = p >> 7;
  const int d = p & 127;
  float mv0 = Mv0[(4*g+0)*DKD + d];
  float mv1 = Mv0[(4*g+1)*DKD + d];
  float mv2 = Mv0[(4*g+2)*DKD + d];
  float mv3 = Mv0[(4*g+3)*DKD + d];
  const float4* w4 = ((const float4*)(w_in + (size_t)b*SEQL*SLOTS)) + g;
  const float*  ep = e_in + (size_t)b*SEQL*DKD + d;
  const float*  ap = a_in + (size_t)b*SEQL*DKD + d;
  float*        rp = r_out + (size_t)b*SEQL*DKD + d;
  const bool wlane = ((threadIdx.x & 15) == 15);

  float4 w0,w1,w2,w3,w4r,w5,w6,w7;
  float  e0,e1,e2,e3,e4,e5,e6,e7;
  float  a0,a1,a2,a3,a4,a5,a6,a7;
  #define LOADT(T, WV, EV, AV) WV = w4[(size_t)(T)*16]; EV = ep[(size_t)(T)*DKD]; AV = ap[(size_t)(T)*DKD];
  LOADT(0,w0,e0,a0) LOADT(1,w1,e1,a1) LOADT(2,w2,e2,a2) LOADT(3,w3,e3,a3)
  LOADT(4,w4r,e4,a4) LOADT(5,w5,e5,a5) LOADT(6,w6,e6,a6) LOADT(7,w7,e7,a7)

  for (int t = 0; t < SEQL; t += 8){
    #define BODY(K, WV, EV, AV) { \
      float r = WV.x*mv0; r = fmaf(WV.y, mv1, r); r = fmaf(WV.z, mv2, r); r = fmaf(WV.w, mv3, r); \
      r = dpp_row_sum16(r); \
      if (wlane) rp[(size_t)(t+K)*DKD] = r; \
      mv0 = fmaf(WV.x, fmaf(-mv0, EV, AV), mv0); \
      mv1 = fmaf(WV.y, fmaf(-mv1, EV, AV), mv1); \
      mv2 = fmaf(WV.z, fmaf(-mv2, EV, AV), mv2); \
      mv3 = fmaf(WV.w, fmaf(-mv3, EV, AV), mv3); \
      int tn = t + K + 8; if (tn >= SEQL) tn = SEQL-1; \
      WV = w4[(size_t)tn*16]; EV = ep[(size_t)tn*DKD]; AV = ap[(size_t)tn*DKD]; }
    BODY(0,w0,e0,a0) BODY(1,w1,e1,a1) BODY(2,w2,e2,a2) BODY(3,w3,e3,a3)
    BODY(4,w4r,e4,a4) BODY(5,w5,e5,a5) BODY(6,w6,e6,a6) BODY(7,w7,e7,a7)
    #undef BODY
  }
}

// ---------------- Kernel P3: f = tanh([read|k] fW^T + fb), out = sigmoid(f pW^T + pb) ----
// 400 blocks. Tile 32 tok x 128 out. K=256 quartered (64). micro 4 tok x 4 out.
__global__ __launch_bounds__(256) void p3_kernel(
    const int* __restrict__ qseq, const float* __restrict__ q_emb,
    const float* __restrict__ r_in, const float* __restrict__ fW,
    const float* __restrict__ fb, const float* __restrict__ pW,
    const float* __restrict__ pb, float* __restrict__ out)
{
  __shared__ float A[32][68];      // one 64-wide k-quarter of [read|k]
  __shared__ float B[128*64];      // 128 out x 64 k swizzled (16 f4 slots)
  const int tid = threadIdx.x;
  const int tx = tid & 31, ty = tid >> 5;
  const int tok0 = blockIdx.x * 32;
  float acc[4][4] = {};
  const int xb = (tx >> 2) & 7;
  for (int q = 0; q < 4; ++q){
    __syncthreads();
    #pragma unroll
    for (int m = 0; m < 2; ++m){   // stage A: 512 f4
      int idx = tid + 256*m;
      int row = idx >> 4, c4 = idx & 15;
      float4 v;
      if (q < 2) v = ((const float4*)r_in)[(size_t)(tok0+row)*32 + q*16 + c4];
      else {
        int qq = qseq[tok0+row];
        v = ((const float4*)q_emb)[(size_t)qq*32 + (q-2)*16 + c4];
      }
      *(float4*)&A[row][c4*4] = v;
    }
    #pragma unroll
    for (int m = 0; m < 8; ++m){   // stage B: 2048 f4 swizzled
      int idx = tid + 256*m;
      int o = idx >> 4, k4 = idx & 15;
      int s = k4 ^ ((o >> 2) & 15);
      *(float4*)&B[o*64 + s*4] = ((const float4*)fW)[(size_t)o*64 + q*16 + k4];
    }
    __syncthreads();
    #pragma unroll
    for (int kk = 0; kk < 16; ++kk){
      float4 rA[4];
      #pragma unroll
      for (int i = 0; i < 4; ++i) rA[i] = *(const float4*)&A[ty*4+i][kk*4];
      #pragma unroll
      for (int j = 0; j < 4; ++j){
        int slot = (kk ^ xb ^ ((j & 1) << 3)) & 15;
        float4 rB = *(const float4*)&B[(tx+32*j)*64 + slot*4];
        #pragma unroll
        for (int i = 0; i < 4; ++i){
          acc[i][j] = fmaf(rA[i].x, rB.x, acc[i][j]);
          acc[i][j] = fmaf(rA[i].y, rB.y, acc[i][j]);
          acc[i][j] = fmaf(rA[i].z, rB.z, acc[i][j]);
          acc[i][j] = fmaf(rA[i].w, rB.w, acc[i][j]);
        }
      }
    }
  }
  const float pbv = pb[0];
  float pacc[4] = {0.f,0.f,0.f,0.f};
  #pragma unroll
  for (int j = 0; j < 4; ++j){
    int o = tx + 32*j;
    float bias = fb[o], pw = pW[o];
    #pragma unroll
    for (int i = 0; i < 4; ++i){
      float f = tanhf_(acc[i][j] + bias);
      pacc[i] = fmaf(f, pw, pacc[i]);
    }
  }
  #pragma unroll
  for (int i = 0; i < 4; ++i){
    float s = pacc[i];
    #pragma unroll
    for (int off = 16; off >= 1; off >>= 1) s += __shfl_xor(s, off);
    if (tx == 0) out[tok0 + ty*4 + i] = sigmoidf_(s + pbv);
  }
}

extern "C" void kernel_launch(void* const* d_in, const int* in_sizes, int n_in,
                              void* d_out, int out_size, void* d_ws, size_t ws_size,
                              hipStream_t stream) {
  const int*   qseq  = (const int*)d_in[0];
  const int*   cseq  = (const int*)d_in[1];
  const float* q_emb = (const float*)d_in[2];
  const float* v_emb = (const float*)d_in[3];
  const float* Mk    = (const float*)d_in[4];
  const float* Mv0   = (const float*)d_in[5];
  const float* eW    = (const float*)d_in[6];
  const float* eb    = (const float*)d_in[7];
  const float* aW    = (const float*)d_in[8];
  const float* ab    = (const float*)d_in[9];
  const float* fW    = (const float*)d_in[10];
  const float* fb    = (const float*)d_in[11];
  const float* pW    = (const float*)d_in[12];
  const float* pb    = (const float*)d_in[13];

  float* w_buf = (float*)d_ws;
  float* e_buf = w_buf + (size_t)NTOK*SLOTS;
  float* a_buf = e_buf + (size_t)NTOK*DKD;
  float* r_buf = a_buf + (size_t)NTOK*DKD;
  float* outp  = (float*)d_out;

  hipLaunchKernelGGL(w_kernel, dim3(NTOK/32), dim3(256), 0, stream,
                     qseq, q_emb, Mk, w_buf);
  hipLaunchKernelGGL(ea_kernel, dim3(NTOK/32), dim3(256), 0, stream,
                     qseq, cseq, v_emb, eW, eb, aW, ab, e_buf, a_buf);
  hipLaunchKernelGGL(scan_kernel, dim3((BATCH*DKD*16)/256), dim3(256), 0, stream,
                     Mv0, w_buf, e_buf, a_buf, r_buf);
  hipLaunchKernelGGL(p3_kernel, dim3(NTOK/32), dim3(256), 0, stream,
                     qseq, q_emb, r_buf, fW, fb, pW, pb, outp);
}

// Round 3
// 64.488 us; speedup vs baseline: 2.5458x; 1.6222x over previous
//
#include <hip/hip_runtime.h>
#include <hip/hip_bf16.h>

#define NQ 10000
#define BATCH 64
#define SEQL 200
#define DKD 128
#define SLOTS 64
#define NTOK (BATCH*SEQL)

typedef __attribute__((ext_vector_type(8))) short bh8;
typedef __attribute__((ext_vector_type(4))) float f32x4;
typedef unsigned short u16;
typedef unsigned int u32;

__device__ __forceinline__ float sigmoidf_(float x){ return 1.0f/(1.0f + __expf(-x)); }
__device__ __forceinline__ float tanhf_(float x){
  float ax = fminf(fabsf(x), 30.0f);
  float t = __expf(-2.0f*ax);
  float r = (1.0f-t)/(1.0f+t);
  return copysignf(r, x);
}
// fp32 -> bf16 round-to-nearest-even (bit pattern)
__device__ __forceinline__ u16 f2b(float x){
  u32 u = __builtin_bit_cast(u32, x);
  u32 r = (u + 0x7FFFu + ((u >> 16) & 1u)) >> 16;
  return (u16)r;
}
// physical byte offset of logical (row, col16) in a row-major LDS tile of
// rowBytes-wide rows, with the G4 XOR swizzle (16-lane stride-row reads
// would otherwise be a 16-way bank conflict).
__device__ __forceinline__ int swz(int row, int col16, int rowBytes){
  return row*rowBytes + ((col16 ^ (row & 7)) << 4);
}

// ---------------- Prep: convert Mk,eW,aW,fW fp32 -> bf16 (147 KB total) ----------------
__global__ __launch_bounds__(256) void prep_kernel(
    const float* __restrict__ Mk, const float* __restrict__ eW,
    const float* __restrict__ aW, const float* __restrict__ fW,
    u16* __restrict__ Mkb, u16* __restrict__ eWb,
    u16* __restrict__ aWb, u16* __restrict__ fWb)
{
  int idx = blockIdx.x*256 + threadIdx.x;   // f4 index, total 18432
  const float* src; u16* dst; int off;
  if (idx < 2048)       { src = Mk; dst = Mkb; off = idx; }
  else if (idx < 6144)  { src = eW; dst = eWb; off = idx - 2048; }
  else if (idx < 10240) { src = aW; dst = aWb; off = idx - 6144; }
  else                  { src = fW; dst = fWb; off = idx - 10240; }
  float4 v = ((const float4*)src)[off];
  short4 h;
  h.x = (short)f2b(v.x); h.y = (short)f2b(v.y);
  h.z = (short)f2b(v.z); h.w = (short)f2b(v.w);
  *(short4*)(dst + (size_t)off*4) = h;
}

// ---------------- WEA: blocks 0..399 = W (softmax(k Mk^T)); 400..799 = E/A ----------------
// 512 thr = 8 waves; 32 tok/block; MFMA 16x16x32 bf16.
__global__ __launch_bounds__(512) void wea_kernel(
    const int* __restrict__ qseq, const int* __restrict__ cseq,
    const float* __restrict__ q_emb, const float* __restrict__ v_emb,
    const u16* __restrict__ Mkb, const u16* __restrict__ eWb,
    const u16* __restrict__ aWb,
    const float* __restrict__ eb, const float* __restrict__ ab,
    float* __restrict__ w_out, float* __restrict__ e_out, float* __restrict__ a_out)
{
  __shared__ __align__(16) char smem[73728];
  char* As = smem;                       // A tile [32 rows][256B]
  char* Bs = smem + 8192;                // W: Mk [64][256B]; EA: [256][256B]
  float* Ls = (float*)(smem + 24576);    // W logits [32][68] f32

  const int tid = threadIdx.x;
  const int l = tid & 63, wv = tid >> 6;
  const bool isW = (blockIdx.x < 400);
  const int tok0 = (isW ? blockIdx.x : blockIdx.x - 400) * 32;

  { // stage A: gather 32 embedding rows, cvt fp32->bf16, swizzled write (1 chunk/thread)
    int row = tid >> 4, c16 = tid & 15;
    const float* src;
    if (isW){ int q = qseq[tok0+row]; src = q_emb + (size_t)q*DKD + c16*8; }
    else    { int x = qseq[tok0+row] + NQ*cseq[tok0+row]; src = v_emb + (size_t)x*DKD + c16*8; }
    float4 v0 = *(const float4*)src;
    float4 v1 = *(const float4*)(src + 4);
    bh8 h;
    h[0]=(short)f2b(v0.x); h[1]=(short)f2b(v0.y); h[2]=(short)f2b(v0.z); h[3]=(short)f2b(v0.w);
    h[4]=(short)f2b(v1.x); h[5]=(short)f2b(v1.y); h[6]=(short)f2b(v1.z); h[7]=(short)f2b(v1.w);
    *(bh8*)(As + swz(row, c16, 256)) = h;
  }
  if (isW){ // stage B = Mk bf16 (64 rows x 16 chunks)
    #pragma unroll
    for (int m = 0; m < 2; ++m){
      int idx = tid + 512*m; int row = idx >> 4, c16 = idx & 15;
      bh8 v = *(const bh8*)(Mkb + (size_t)row*DKD + c16*8);
      *(bh8*)(Bs + swz(row, c16, 256)) = v;
    }
  } else {  // stage B = [eW; aW] bf16 (256 rows x 16 chunks)
    #pragma unroll
    for (int m = 0; m < 8; ++m){
      int idx = tid + 512*m; int row = idx >> 4, c16 = idx & 15;
      const u16* src = (row < 128) ? (eWb + (size_t)row*DKD) : (aWb + (size_t)(row-128)*DKD);
      bh8 v = *(const bh8*)(src + c16*8);
      *(bh8*)(Bs + swz(row, c16, 256)) = v;
    }
  }
  __syncthreads();

  if (isW){
    const int m = wv & 1, n = wv >> 1;        // 8 waves -> 8 output tiles
    f32x4 acc = {0.f,0.f,0.f,0.f};
    #pragma unroll
    for (int kc = 0; kc < 4; ++kc){
      bh8 af = *(const bh8*)(As + swz(m*16 + (l&15), kc*4 + (l>>4), 256));
      bh8 bf = *(const bh8*)(Bs + swz(n*16 + (l&15), kc*4 + (l>>4), 256));
      acc = __builtin_amdgcn_mfma_f32_16x16x32_bf16(af, bf, acc, 0, 0, 0);
    }
    #pragma unroll
    for (int r = 0; r < 4; ++r){
      int tok = m*16 + (l>>4)*4 + r, out = n*16 + (l&15);
      Ls[tok*68 + out] = acc[r];
    }
    __syncthreads();
    // softmax: wave wv owns tokens 4wv..4wv+3; lane = slot
    #pragma unroll
    for (int i = 0; i < 4; ++i){
      int tok = wv*4 + i;
      float x = Ls[tok*68 + l];
      float mx = x;
      #pragma unroll
      for (int off = 32; off >= 1; off >>= 1) mx = fmaxf(mx, __shfl_xor(mx, off));
      float p = __expf(x - mx);
      float s = p;
      #pragma unroll
      for (int off = 32; off >= 1; off >>= 1) s += __shfl_xor(s, off);
      w_out[(size_t)(tok0+tok)*SLOTS + l] = p / s;
    }
  } else {
    const int m = wv & 1, nq = (wv >> 1) * 4; // 4 n-tiles per wave
    f32x4 acc[4] = {{0.f,0.f,0.f,0.f},{0.f,0.f,0.f,0.f},{0.f,0.f,0.f,0.f},{0.f,0.f,0.f,0.f}};
    #pragma unroll
    for (int kc = 0; kc < 4; ++kc){
      bh8 af = *(const bh8*)(As + swz(m*16 + (l&15), kc*4 + (l>>4), 256));
      #pragma unroll
      for (int j = 0; j < 4; ++j){
        bh8 bf = *(const bh8*)(Bs + swz((nq+j)*16 + (l&15), kc*4 + (l>>4), 256));
        acc[j] = __builtin_amdgcn_mfma_f32_16x16x32_bf16(af, bf, acc[j], 0, 0, 0);
      }
    }
    #pragma unroll
    for (int j = 0; j < 4; ++j){
      int out = (nq+j)*16 + (l&15);
      bool is_e = (out < 128);
      int d = out & 127;
      float bias = is_e ? eb[d] : ab[d];
      #pragma unroll
      for (int r = 0; r < 4; ++r){
        int tok = tok0 + m*16 + (l>>4)*4 + r;
        float xv = acc[j][r] + bias;
        if (is_e) e_out[(size_t)tok*DKD + d] = sigmoidf_(xv);
        else      a_out[(size_t)tok*DKD + d] = tanhf_(xv);
      }
    }
  }
}

// ---------------- Scan: DPP row-sum reduce + distance-8 prefetch; emits read as bf16 ----
__device__ __forceinline__ float dpp_row_sum16(float x){
  float t;
  t = __builtin_bit_cast(float, __builtin_amdgcn_update_dpp(0, __builtin_bit_cast(int,x), 0x111, 0xf, 0xf, true)); x += t; // row_shr:1
  t = __builtin_bit_cast(float, __builtin_amdgcn_update_dpp(0, __builtin_bit_cast(int,x), 0x112, 0xf, 0xf, true)); x += t; // row_shr:2
  t = __builtin_bit_cast(float, __builtin_amdgcn_update_dpp(0, __builtin_bit_cast(int,x), 0x114, 0xf, 0xf, true)); x += t; // row_shr:4
  t = __builtin_bit_cast(float, __builtin_amdgcn_update_dpp(0, __builtin_bit_cast(int,x), 0x118, 0xf, 0xf, true)); x += t; // row_shr:8
  return x;  // lane 15 (mod 16) holds the 16-lane sum
}

__global__ __launch_bounds__(256) void scan_kernel(
    const float* __restrict__ Mv0,
    const float* __restrict__ w_in, const float* __restrict__ e_in,
    const float* __restrict__ a_in, u16* __restrict__ r16)
{
  const int gid = blockIdx.x*256 + threadIdx.x;
  const int g = gid & 15;           // owns slots 4g..4g+3
  const int p = gid >> 4;           // (b,d)
  const int b = p >> 7;
  const int d = p & 127;
  float mv0 = Mv0[(4*g+0)*DKD + d];
  float mv1 = Mv0[(4*g+1)*DKD + d];
  float mv2 = Mv0[(4*g+2)*DKD + d];
  float mv3 = Mv0[(4*g+3)*DKD + d];
  const float4* w4 = ((const float4*)(w_in + (size_t)b*SEQL*SLOTS)) + g;
  const float*  ep = e_in + (size_t)b*SEQL*DKD + d;
  const float*  ap = a_in + (size_t)b*SEQL*DKD + d;
  u16*          rp = r16  + (size_t)b*SEQL*DKD + d;
  const bool wlane = ((threadIdx.x & 15) == 15);

  float4 w0,w1,w2,w3,w4r,w5,w6,w7;
  float  e0,e1,e2,e3,e4,e5,e6,e7;
  float  a0,a1,a2,a3,a4,a5,a6,a7;
  #define LOADT(T, WV, EV, AV) WV = w4[(size_t)(T)*16]; EV = ep[(size_t)(T)*DKD]; AV = ap[(size_t)(T)*DKD];
  LOADT(0,w0,e0,a0) LOADT(1,w1,e1,a1) LOADT(2,w2,e2,a2) LOADT(3,w3,e3,a3)
  LOADT(4,w4r,e4,a4) LOADT(5,w5,e5,a5) LOADT(6,w6,e6,a6) LOADT(7,w7,e7,a7)
  #undef LOADT

  for (int t = 0; t < SEQL; t += 8){
    #define BODY(K, WV, EV, AV) { \
      float r = WV.x*mv0; r = fmaf(WV.y, mv1, r); r = fmaf(WV.z, mv2, r); r = fmaf(WV.w, mv3, r); \
      r = dpp_row_sum16(r); \
      if (wlane) rp[(size_t)(t+K)*DKD] = f2b(r); \
      mv0 = fmaf(WV.x, fmaf(-mv0, EV, AV), mv0); \
      mv1 = fmaf(WV.y, fmaf(-mv1, EV, AV), mv1); \
      mv2 = fmaf(WV.z, fmaf(-mv2, EV, AV), mv2); \
      mv3 = fmaf(WV.w, fmaf(-mv3, EV, AV), mv3); \
      int tn = t + K + 8; if (tn >= SEQL) tn = SEQL-1; \
      WV = w4[(size_t)tn*16]; EV = ep[(size_t)tn*DKD]; AV = ap[(size_t)tn*DKD]; }
    BODY(0,w0,e0,a0) BODY(1,w1,e1,a1) BODY(2,w2,e2,a2) BODY(3,w3,e3,a3)
    BODY(4,w4r,e4,a4) BODY(5,w5,e5,a5) BODY(6,w6,e6,a6) BODY(7,w7,e7,a7)
    #undef BODY
  }
}

// ---------------- P3: f = tanh([read|k] fW^T + fb); out = sigmoid(f pW + pb) ----------------
// 512 thr = 8 waves; 32 tok/block; A = [r16 | k] bf16 (K=256), B = fWb. LDS exactly 80 KiB.
__global__ __launch_bounds__(512) void p3_kernel(
    const int* __restrict__ qseq, const float* __restrict__ q_emb,
    const u16* __restrict__ r16, const u16* __restrict__ fWb,
    const float* __restrict__ fb, const float* __restrict__ pW,
    const float* __restrict__ pb, float* __restrict__ out)
{
  __shared__ __align__(16) char smem[81920];
  char* As = smem;            // [32 rows][512B]
  char* Bs = smem + 16384;    // [128 rows][512B]

  const int tid = threadIdx.x;
  const int l = tid & 63, wv = tid >> 6;
  const int tok0 = blockIdx.x * 32;

  #pragma unroll
  for (int m = 0; m < 2; ++m){   // stage A: 1024 chunks (rows 512B = 32 chunks)
    int idx = tid + 512*m; int row = idx >> 5, c16 = idx & 31;
    bh8 v;
    if (c16 < 16){
      v = *(const bh8*)(r16 + (size_t)(tok0+row)*DKD + c16*8);
    } else {
      int q = qseq[tok0+row];
      const float* s = q_emb + (size_t)q*DKD + (c16-16)*8;
      float4 v0 = *(const float4*)s, v1 = *(const float4*)(s + 4);
      v[0]=(short)f2b(v0.x); v[1]=(short)f2b(v0.y); v[2]=(short)f2b(v0.z); v[3]=(short)f2b(v0.w);
      v[4]=(short)f2b(v1.x); v[5]=(short)f2b(v1.y); v[6]=(short)f2b(v1.z); v[7]=(short)f2b(v1.w);
    }
    *(bh8*)(As + swz(row, c16, 512)) = v;
  }
  #pragma unroll
  for (int m = 0; m < 8; ++m){   // stage B: 4096 chunks
    int idx = tid + 512*m; int row = idx >> 5, c16 = idx & 31;
    bh8 v = *(const bh8*)(fWb + (size_t)row*256 + c16*8);
    *(bh8*)(Bs + swz(row, c16, 512)) = v;
  }
  __syncthreads();

  const int m = wv & 1, np = (wv >> 1) * 2;   // 2 n-tiles per wave
  f32x4 acc[2] = {{0.f,0.f,0.f,0.f},{0.f,0.f,0.f,0.f}};
  #pragma unroll
  for (int kc = 0; kc < 8; ++kc){
    bh8 af = *(const bh8*)(As + swz(m*16 + (l&15), kc*4 + (l>>4), 512));
    #pragma unroll
    for (int j = 0; j < 2; ++j){
      bh8 bf = *(const bh8*)(Bs + swz((np+j)*16 + (l&15), kc*4 + (l>>4), 512));
      acc[j] = __builtin_amdgcn_mfma_f32_16x16x32_bf16(af, bf, acc[j], 0, 0, 0);
    }
  }
  // per-lane partial p over this wave's 32 out-columns
  float pp[4] = {0.f,0.f,0.f,0.f};
  #pragma unroll
  for (int j = 0; j < 2; ++j){
    int o = (np+j)*16 + (l&15);
    float bias = fb[o], pw = pW[o];
    #pragma unroll
    for (int r = 0; r < 4; ++r){
      float f = tanhf_(acc[j][r] + bias);
      pp[r] = fmaf(f, pw, pp[r]);
    }
  }
  #pragma unroll
  for (int r = 0; r < 4; ++r){   // reduce across the 16 out-lanes
    pp[r] += __shfl_xor(pp[r], 1);
    pp[r] += __shfl_xor(pp[r], 2);
    pp[r] += __shfl_xor(pp[r], 4);
    pp[r] += __shfl_xor(pp[r], 8);
  }
  __syncthreads();
  float* pbuf = (float*)smem;    // overlay on As (done with it): [8 waves][32 tok]
  if ((l & 15) == 0){
    #pragma unroll
    for (int r = 0; r < 4; ++r){
      int tok = m*16 + (l>>4)*4 + r;
      pbuf[wv*32 + tok] = pp[r];
    }
  }
  __syncthreads();
  if (tid < 32){
    int mm = tid >> 4;   // token's m-half -> waves with wv&1 == mm
    float s = pbuf[(mm+0)*32 + tid] + pbuf[(mm+2)*32 + tid]
            + pbuf[(mm+4)*32 + tid] + pbuf[(mm+6)*32 + tid];
    out[tok0 + tid] = sigmoidf_(s + pb[0]);
  }
}

extern "C" void kernel_launch(void* const* d_in, const int* in_sizes, int n_in,
                              void* d_out, int out_size, void* d_ws, size_t ws_size,
                              hipStream_t stream) {
  const int*   qseq  = (const int*)d_in[0];
  const int*   cseq  = (const int*)d_in[1];
  const float* q_emb = (const float*)d_in[2];
  const float* v_emb = (const float*)d_in[3];
  const float* Mk    = (const float*)d_in[4];
  const float* Mv0   = (const float*)d_in[5];
  const float* eW    = (const float*)d_in[6];
  const float* eb    = (const float*)d_in[7];
  const float* aW    = (const float*)d_in[8];
  const float* ab    = (const float*)d_in[9];
  const float* fW    = (const float*)d_in[10];
  const float* fb    = (const float*)d_in[11];
  const float* pW    = (const float*)d_in[12];
  const float* pb    = (const float*)d_in[13];

  char* ws = (char*)d_ws;
  float* w_buf = (float*)ws;                                   // 12800*64*4   = 3,276,800
  float* e_buf = (float*)(ws + 3276800);                       // 12800*128*4  = 6,553,600
  float* a_buf = (float*)(ws + 9830400);                       // 6,553,600
  u16*   r16   = (u16*)  (ws + 16384000);                      // 12800*128*2  = 3,276,800
  u16*   Mkb   = (u16*)  (ws + 19660800);                      // 16,384
  u16*   eWb   = (u16*)  (ws + 19677184);                      // 32,768
  u16*   aWb   = (u16*)  (ws + 19709952);                      // 32,768
  u16*   fWb   = (u16*)  (ws + 19742720);                      // 65,536  (end ~19.8 MB)
  float* outp  = (float*)d_out;

  hipLaunchKernelGGL(prep_kernel, dim3(72), dim3(256), 0, stream,
                     Mk, eW, aW, fW, Mkb, eWb, aWb, fWb);
  hipLaunchKernelGGL(wea_kernel, dim3(800), dim3(512), 0, stream,
                     qseq, cseq, q_emb, v_emb, Mkb, eWb, aWb, eb, ab,
                     w_buf, e_buf, a_buf);
  hipLaunchKernelGGL(scan_kernel, dim3((BATCH*DKD*16)/256), dim3(256), 0, stream,
                     Mv0, w_buf, e_buf, a_buf, r16);
  hipLaunchKernelGGL(p3_kernel, dim3(NTOK/32), dim3(512), 0, stream,
                     qseq, q_emb, r16, fWb, fb, pW, pb, outp);
}

// Round 4
// 57.310 us; speedup vs baseline: 2.8646x; 1.1252x over previous
//
#include <hip/hip_runtime.h>
#include <hip/hip_bf16.h>

#define NQ 10000
#define BATCH 64
#define SEQL 200
#define DKD 128
#define SLOTS 64
#define NTOK (BATCH*SEQL)

typedef __attribute__((ext_vector_type(8))) short bh8;
typedef __attribute__((ext_vector_type(4))) float f32x4;
typedef unsigned short u16;
typedef unsigned int u32;

__device__ __forceinline__ float sigmoidf_(float x){ return 1.0f/(1.0f + __expf(-x)); }
__device__ __forceinline__ float tanhf_(float x){
  float ax = fminf(fabsf(x), 30.0f);
  float t = __expf(-2.0f*ax);
  float r = (1.0f-t)/(1.0f+t);
  return copysignf(r, x);
}
// fp32 -> bf16 round-to-nearest-even (bit pattern)
__device__ __forceinline__ u16 f2b(float x){
  u32 u = __builtin_bit_cast(u32, x);
  u32 r = (u + 0x7FFFu + ((u >> 16) & 1u)) >> 16;
  return (u16)r;
}
// convert 8 consecutive fp32 at s -> bh8
__device__ __forceinline__ bh8 cvt8(const float* s){
  float4 v0 = *(const float4*)s, v1 = *(const float4*)(s + 4);
  bh8 h;
  h[0]=(short)f2b(v0.x); h[1]=(short)f2b(v0.y); h[2]=(short)f2b(v0.z); h[3]=(short)f2b(v0.w);
  h[4]=(short)f2b(v1.x); h[5]=(short)f2b(v1.y); h[6]=(short)f2b(v1.z); h[7]=(short)f2b(v1.w);
  return h;
}
// physical byte offset of logical (row, col16) in a row-major LDS tile,
// G4 XOR swizzle (16-lane stride-row MFMA fragment reads otherwise 16-way conflict)
__device__ __forceinline__ int swz(int row, int col16, int rowBytes){
  return row*rowBytes + ((col16 ^ (row & 7)) << 4);
}

// ---------------- WEA: blocks 0..399 = W (softmax(k Mk^T)); 400..799 = E/A ----------------
// 512 thr = 8 waves; 32 tok/block; MFMA 16x16x32 bf16. Weights converted fp32->bf16 in staging.
__global__ __launch_bounds__(512) void wea_kernel(
    const int* __restrict__ qseq, const int* __restrict__ cseq,
    const float* __restrict__ q_emb, const float* __restrict__ v_emb,
    const float* __restrict__ Mk, const float* __restrict__ eW,
    const float* __restrict__ aW,
    const float* __restrict__ eb, const float* __restrict__ ab,
    float* __restrict__ w_out, float* __restrict__ e_out, float* __restrict__ a_out)
{
  __shared__ __align__(16) char smem[73728];
  char* As = smem;                       // A tile [32 rows][256B]
  char* Bs = smem + 8192;                // W: Mk [64][256B]; EA: [256][256B]
  float* Ls = (float*)(smem + 24576);    // W logits [32][68] f32

  const int tid = threadIdx.x;
  const int l = tid & 63, wv = tid >> 6;
  const bool isW = (blockIdx.x < 400);
  const int tok0 = (isW ? blockIdx.x : blockIdx.x - 400) * 32;

  { // stage A: gather 32 embedding rows, cvt fp32->bf16, swizzled write (1 chunk/thread)
    int row = tid >> 4, c16 = tid & 15;
    const float* src;
    if (isW){ int q = qseq[tok0+row]; src = q_emb + (size_t)q*DKD + c16*8; }
    else    { int x = qseq[tok0+row] + NQ*cseq[tok0+row]; src = v_emb + (size_t)x*DKD + c16*8; }
    *(bh8*)(As + swz(row, c16, 256)) = cvt8(src);
  }
  if (isW){ // stage B = Mk (64 rows x 16 chunks), fp32 -> bf16
    #pragma unroll
    for (int m = 0; m < 2; ++m){
      int idx = tid + 512*m; int row = idx >> 4, c16 = idx & 15;
      *(bh8*)(Bs + swz(row, c16, 256)) = cvt8(Mk + (size_t)row*DKD + c16*8);
    }
  } else {  // stage B = [eW; aW] (256 rows x 16 chunks), fp32 -> bf16
    #pragma unroll
    for (int m = 0; m < 8; ++m){
      int idx = tid + 512*m; int row = idx >> 4, c16 = idx & 15;
      const float* src = (row < 128) ? (eW + (size_t)row*DKD) : (aW + (size_t)(row-128)*DKD);
      *(bh8*)(Bs + swz(row, c16, 256)) = cvt8(src + c16*8);
    }
  }
  __syncthreads();

  if (isW){
    const int m = wv & 1, n = wv >> 1;        // 8 waves -> 8 output tiles
    f32x4 acc = {0.f,0.f,0.f,0.f};
    #pragma unroll
    for (int kc = 0; kc < 4; ++kc){
      bh8 af = *(const bh8*)(As + swz(m*16 + (l&15), kc*4 + (l>>4), 256));
      bh8 bf = *(const bh8*)(Bs + swz(n*16 + (l&15), kc*4 + (l>>4), 256));
      acc = __builtin_amdgcn_mfma_f32_16x16x32_bf16(af, bf, acc, 0, 0, 0);
    }
    #pragma unroll
    for (int r = 0; r < 4; ++r){
      int tok = m*16 + (l>>4)*4 + r, out = n*16 + (l&15);
      Ls[tok*68 + out] = acc[r];
    }
    __syncthreads();
    // softmax: wave wv owns tokens 4wv..4wv+3; lane = slot
    #pragma unroll
    for (int i = 0; i < 4; ++i){
      int tok = wv*4 + i;
      float x = Ls[tok*68 + l];
      float mx = x;
      #pragma unroll
      for (int off = 32; off >= 1; off >>= 1) mx = fmaxf(mx, __shfl_xor(mx, off));
      float p = __expf(x - mx);
      float s = p;
      #pragma unroll
      for (int off = 32; off >= 1; off >>= 1) s += __shfl_xor(s, off);
      w_out[(size_t)(tok0+tok)*SLOTS + l] = p / s;
    }
  } else {
    const int m = wv & 1, nq = (wv >> 1) * 4; // 4 n-tiles per wave
    f32x4 acc[4] = {{0.f,0.f,0.f,0.f},{0.f,0.f,0.f,0.f},{0.f,0.f,0.f,0.f},{0.f,0.f,0.f,0.f}};
    #pragma unroll
    for (int kc = 0; kc < 4; ++kc){
      bh8 af = *(const bh8*)(As + swz(m*16 + (l&15), kc*4 + (l>>4), 256));
      #pragma unroll
      for (int j = 0; j < 4; ++j){
        bh8 bf = *(const bh8*)(Bs + swz((nq+j)*16 + (l&15), kc*4 + (l>>4), 256));
        acc[j] = __builtin_amdgcn_mfma_f32_16x16x32_bf16(af, bf, acc[j], 0, 0, 0);
      }
    }
    #pragma unroll
    for (int j = 0; j < 4; ++j){
      int out = (nq+j)*16 + (l&15);
      bool is_e = (out < 128);
      int d = out & 127;
      float bias = is_e ? eb[d] : ab[d];
      #pragma unroll
      for (int r = 0; r < 4; ++r){
        int tok = tok0 + m*16 + (l>>4)*4 + r;
        float xv = acc[j][r] + bias;
        if (is_e) e_out[(size_t)tok*DKD + d] = sigmoidf_(xv);
        else      a_out[(size_t)tok*DKD + d] = tanhf_(xv);
      }
    }
  }
}

// ---------------- Scan: LDS double-buffered chunks (Tc=32), per-b blocks ----------------
__device__ __forceinline__ float dpp_row_sum16(float x){
  float t;
  t = __builtin_bit_cast(float, __builtin_amdgcn_update_dpp(0, __builtin_bit_cast(int,x), 0x111, 0xf, 0xf, true)); x += t; // row_shr:1
  t = __builtin_bit_cast(float, __builtin_amdgcn_update_dpp(0, __builtin_bit_cast(int,x), 0x112, 0xf, 0xf, true)); x += t; // row_shr:2
  t = __builtin_bit_cast(float, __builtin_amdgcn_update_dpp(0, __builtin_bit_cast(int,x), 0x114, 0xf, 0xf, true)); x += t; // row_shr:4
  t = __builtin_bit_cast(float, __builtin_amdgcn_update_dpp(0, __builtin_bit_cast(int,x), 0x118, 0xf, 0xf, true)); x += t; // row_shr:8
  return x;  // lane 15 (mod 16) holds the 16-lane sum
}

#define TC 32
#define NCHUNK 7   // 7*32 = 224 >= 200; tail iters compute garbage, stores guarded

__global__ __launch_bounds__(256) void scan_kernel(
    const float* __restrict__ Mv0,
    const float* __restrict__ w_in, const float* __restrict__ e_in,
    const float* __restrict__ a_in, u16* __restrict__ r16)
{
  // block = (b, 16 consecutive d). 512 blocks, 256 thr.
  __shared__ float wS[2][TC][64];    // 16 KiB   (reads: 2-way bcast, free)
  __shared__ float eS[2][16][36];    // 4.5 KiB  (transposed [d][t], pad 36)
  __shared__ float aS[2][16][36];
  const int tid = threadIdx.x;
  const int b  = blockIdx.x >> 3;
  const int d0 = (blockIdx.x & 7) << 4;
  const int c  = tid >> 4;          // chain: d = d0 + c
  const int g  = tid & 15;          // slot quad: slots 4g..4g+3
  const int d  = d0 + c;

  float mv0 = Mv0[(4*g+0)*DKD + d];
  float mv1 = Mv0[(4*g+1)*DKD + d];
  float mv2 = Mv0[(4*g+2)*DKD + d];
  float mv3 = Mv0[(4*g+3)*DKD + d];

  // staging roles
  const int st_t = tid & 31;        // t within chunk
  const int st_j = tid >> 5;        // chains st_j and st_j+8
  const float4* wsrc = (const float4*)(w_in + (size_t)b*SEQL*SLOTS);
  const float*  ebase = e_in + ((size_t)b*SEQL + st_t)*DKD + d0;
  const float*  abase = a_in + ((size_t)b*SEQL + st_t)*DKD + d0;
  u16* rp = r16 + (size_t)b*SEQL*DKD + d;
  const bool wlane = (g == 15);

  { // prologue: stage chunk 0
    float4 wA = wsrc[tid], wB = wsrc[tid + 256];
    float e0 = ebase[st_j],     e1 = ebase[st_j + 8];
    float a0 = abase[st_j],     a1 = abase[st_j + 8];
    ((float4*)wS[0])[tid] = wA; ((float4*)wS[0])[tid + 256] = wB;
    eS[0][st_j][st_t] = e0; eS[0][st_j+8][st_t] = e1;
    aS[0][st_j][st_t] = a0; aS[0][st_j+8][st_t] = a1;
    __syncthreads();
  }

  int cur = 0;
  for (int ck = 0; ck < NCHUNK; ++ck){
    const int T0 = ck * TC;
    float4 wA, wB; float e0, e1, a0, a1;
    if (ck < NCHUNK-1){   // issue next chunk's global loads NOW (hide under compute)
      const int T0n = T0 + TC;
      wA = wsrc[T0n*16 + tid]; wB = wsrc[T0n*16 + tid + 256];
      e0 = ebase[(size_t)T0n*DKD + st_j]; e1 = ebase[(size_t)T0n*DKD + st_j + 8];
      a0 = abase[(size_t)T0n*DKD + st_j]; a1 = abase[(size_t)T0n*DKD + st_j + 8];
    }
    // compute 32 iters from buf cur
    #pragma unroll
    for (int u = 0; u < TC/4; ++u){
      float eq[4], aq[4];
      *(float4*)eq = *(const float4*)&eS[cur][c][u*4];
      *(float4*)aq = *(const float4*)&aS[cur][c][u*4];
      #pragma unroll
      for (int v = 0; v < 4; ++v){
        const int tt = u*4 + v;
        float4 wq = *(const float4*)&wS[cur][tt][g*4];
        float r = wq.x*mv0; r = fmaf(wq.y, mv1, r); r = fmaf(wq.z, mv2, r); r = fmaf(wq.w, mv3, r);
        r = dpp_row_sum16(r);
        if ((T0 + tt) < SEQL && wlane) rp[(size_t)(T0+tt)*DKD] = f2b(r);
        const float ev = eq[v], av = aq[v];
        mv0 = fmaf(wq.x, fmaf(-mv0, ev, av), mv0);
        mv1 = fmaf(wq.y, fmaf(-mv1, ev, av), mv1);
        mv2 = fmaf(wq.z, fmaf(-mv2, ev, av), mv2);
        mv3 = fmaf(wq.w, fmaf(-mv3, ev, av), mv3);
      }
    }
    // write staged data into buf cur^1, then barrier
    if (ck < NCHUNK-1){
      ((float4*)wS[cur^1])[tid] = wA; ((float4*)wS[cur^1])[tid + 256] = wB;
      eS[cur^1][st_j][st_t] = e0; eS[cur^1][st_j+8][st_t] = e1;
      aS[cur^1][st_j][st_t] = a0; aS[cur^1][st_j+8][st_t] = a1;
      __syncthreads();
      cur ^= 1;
    }
  }
}

// ---------------- P3: f = tanh([read|k] fW^T + fb); out = sigmoid(f pW + pb) ----------------
// 512 thr = 8 waves; 32 tok/block; A = [r16 | k] bf16 (K=256), B = fW cvt'd. LDS 80 KiB.
__global__ __launch_bounds__(512) void p3_kernel(
    const int* __restrict__ qseq, const float* __restrict__ q_emb,
    const u16* __restrict__ r16, const float* __restrict__ fW,
    const float* __restrict__ fb, const float* __restrict__ pW,
    const float* __restrict__ pb, float* __restrict__ out)
{
  __shared__ __align__(16) char smem[81920];
  char* As = smem;            // [32 rows][512B]
  char* Bs = smem + 16384;    // [128 rows][512B]

  const int tid = threadIdx.x;
  const int l = tid & 63, wv = tid >> 6;
  const int tok0 = blockIdx.x * 32;

  #pragma unroll
  for (int m = 0; m < 2; ++m){   // stage A: 1024 chunks (rows 512B = 32 chunks)
    int idx = tid + 512*m; int row = idx >> 5, c16 = idx & 31;
    bh8 v;
    if (c16 < 16){
      v = *(const bh8*)(r16 + (size_t)(tok0+row)*DKD + c16*8);
    } else {
      int q = qseq[tok0+row];
      v = cvt8(q_emb + (size_t)q*DKD + (c16-16)*8);
    }
    *(bh8*)(As + swz(row, c16, 512)) = v;
  }
  #pragma unroll
  for (int m = 0; m < 8; ++m){   // stage B: 4096 chunks, fp32 fW -> bf16
    int idx = tid + 512*m; int row = idx >> 5, c16 = idx & 31;
    *(bh8*)(Bs + swz(row, c16, 512)) = cvt8(fW + (size_t)row*256 + c16*8);
  }
  __syncthreads();

  const int m = wv & 1, np = (wv >> 1) * 2;   // 2 n-tiles per wave
  f32x4 acc[2] = {{0.f,0.f,0.f,0.f},{0.f,0.f,0.f,0.f}};
  #pragma unroll
  for (int kc = 0; kc < 8; ++kc){
    bh8 af = *(const bh8*)(As + swz(m*16 + (l&15), kc*4 + (l>>4), 512));
    #pragma unroll
    for (int j = 0; j < 2; ++j){
      bh8 bf = *(const bh8*)(Bs + swz((np+j)*16 + (l&15), kc*4 + (l>>4), 512));
      acc[j] = __builtin_amdgcn_mfma_f32_16x16x32_bf16(af, bf, acc[j], 0, 0, 0);
    }
  }
  // per-lane partial p over this wave's 32 out-columns
  float pp[4] = {0.f,0.f,0.f,0.f};
  #pragma unroll
  for (int j = 0; j < 2; ++j){
    int o = (np+j)*16 + (l&15);
    float bias = fb[o], pw = pW[o];
    #pragma unroll
    for (int r = 0; r < 4; ++r){
      float f = tanhf_(acc[j][r] + bias);
      pp[r] = fmaf(f, pw, pp[r]);
    }
  }
  #pragma unroll
  for (int r = 0; r < 4; ++r){   // reduce across the 16 out-lanes
    pp[r] += __shfl_xor(pp[r], 1);
    pp[r] += __shfl_xor(pp[r], 2);
    pp[r] += __shfl_xor(pp[r], 4);
    pp[r] += __shfl_xor(pp[r], 8);
  }
  __syncthreads();
  float* pbuf = (float*)smem;    // overlay on As (done with it): [8 waves][32 tok]
  if ((l & 15) == 0){
    #pragma unroll
    for (int r = 0; r < 4; ++r){
      int tok = m*16 + (l>>4)*4 + r;
      pbuf[wv*32 + tok] = pp[r];
    }
  }
  __syncthreads();
  if (tid < 32){
    int mm = tid >> 4;   // token's m-half -> waves with wv&1 == mm
    float s = pbuf[(mm+0)*32 + tid] + pbuf[(mm+2)*32 + tid]
            + pbuf[(mm+4)*32 + tid] + pbuf[(mm+6)*32 + tid];
    out[tok0 + tid] = sigmoidf_(s + pb[0]);
  }
}

extern "C" void kernel_launch(void* const* d_in, const int* in_sizes, int n_in,
                              void* d_out, int out_size, void* d_ws, size_t ws_size,
                              hipStream_t stream) {
  const int*   qseq  = (const int*)d_in[0];
  const int*   cseq  = (const int*)d_in[1];
  const float* q_emb = (const float*)d_in[2];
  const float* v_emb = (const float*)d_in[3];
  const float* Mk    = (const float*)d_in[4];
  const float* Mv0   = (const float*)d_in[5];
  const float* eW    = (const float*)d_in[6];
  const float* eb    = (const float*)d_in[7];
  const float* aW    = (const float*)d_in[8];
  const float* ab    = (const float*)d_in[9];
  const float* fW    = (const float*)d_in[10];
  const float* fb    = (const float*)d_in[11];
  const float* pW    = (const float*)d_in[12];
  const float* pb    = (const float*)d_in[13];

  char* ws = (char*)d_ws;
  float* w_buf = (float*)ws;                                   // 12800*64*4   = 3,276,800
  float* e_buf = (float*)(ws + 3276800);                       // 12800*128*4  = 6,553,600
  float* a_buf = (float*)(ws + 9830400);                       // 6,553,600
  u16*   r16   = (u16*)  (ws + 16384000);                      // 12800*128*2  = 3,276,800  (end ~19.7 MB)
  float* outp  = (float*)d_out;

  hipLaunchKernelGGL(wea_kernel, dim3(800), dim3(512), 0, stream,
                     qseq, cseq, q_emb, v_emb, Mk, eW, aW, eb, ab,
                     w_buf, e_buf, a_buf);
  hipLaunchKernelGGL(scan_kernel, dim3(512), dim3(256), 0, stream,
                     Mv0, w_buf, e_buf, a_buf, r16);
  hipLaunchKernelGGL(p3_kernel, dim3(NTOK/32), dim3(512), 0, stream,
                     qseq, q_emb, r16, fW, fb, pW, pb, outp);
}

// Round 5
// 50.616 us; speedup vs baseline: 3.2435x; 1.1323x over previous
//
#include <hip/hip_runtime.h>
#include <hip/hip_bf16.h>

#define NQ 10000
#define BATCH 64
#define SEQL 200
#define DKD 128
#define SLOTS 64
#define NTOK (BATCH*SEQL)

typedef __attribute__((ext_vector_type(8))) short bh8;
typedef __attribute__((ext_vector_type(4))) float f32x4;
typedef unsigned short u16;
typedef unsigned int u32;

__device__ __forceinline__ float sigmoidf_(float x){ return 1.0f/(1.0f + __expf(-x)); }
__device__ __forceinline__ float tanhf_(float x){
  float ax = fminf(fabsf(x), 30.0f);
  float t = __expf(-2.0f*ax);
  float r = (1.0f-t)/(1.0f+t);
  return copysignf(r, x);
}
// fp32 -> bf16 round-to-nearest-even (bit pattern)
__device__ __forceinline__ u16 f2b(float x){
  u32 u = __builtin_bit_cast(u32, x);
  u32 r = (u + 0x7FFFu + ((u >> 16) & 1u)) >> 16;
  return (u16)r;
}
// convert 8 consecutive fp32 at s -> bh8
__device__ __forceinline__ bh8 cvt8(const float* s){
  float4 v0 = *(const float4*)s, v1 = *(const float4*)(s + 4);
  bh8 h;
  h[0]=(short)f2b(v0.x); h[1]=(short)f2b(v0.y); h[2]=(short)f2b(v0.z); h[3]=(short)f2b(v0.w);
  h[4]=(short)f2b(v1.x); h[5]=(short)f2b(v1.y); h[6]=(short)f2b(v1.z); h[7]=(short)f2b(v1.w);
  return h;
}
// physical byte offset of logical (row, col16) in a row-major LDS tile,
// G4 XOR swizzle (16-lane stride-row MFMA fragment reads otherwise 16-way conflict)
__device__ __forceinline__ int swz(int row, int col16, int rowBytes){
  return row*rowBytes + ((col16 ^ (row & 7)) << 4);
}

// ---------------- WEA: blocks 0..399 = W (softmax(k Mk^T)); 400..799 = E/A ----------------
// 512 thr = 8 waves; 32 tok/block; MFMA 16x16x32 bf16.
// E/A outputs are written TRANSPOSED: eT/aT[b][d][t] (t-contiguous float4 per lane).
__global__ __launch_bounds__(512) void wea_kernel(
    const int* __restrict__ qseq, const int* __restrict__ cseq,
    const float* __restrict__ q_emb, const float* __restrict__ v_emb,
    const float* __restrict__ Mk, const float* __restrict__ eW,
    const float* __restrict__ aW,
    const float* __restrict__ eb, const float* __restrict__ ab,
    float* __restrict__ w_out, float* __restrict__ eT, float* __restrict__ aT)
{
  __shared__ __align__(16) char smem[73728];
  char* As = smem;                       // A tile [32 rows][256B]
  char* Bs = smem + 8192;                // W: Mk [64][256B]; EA: [256][256B]
  float* Ls = (float*)(smem + 24576);    // W logits [32][68] f32

  const int tid = threadIdx.x;
  const int l = tid & 63, wv = tid >> 6;
  const bool isW = (blockIdx.x < 400);
  const int tok0 = (isW ? blockIdx.x : blockIdx.x - 400) * 32;

  { // stage A: gather 32 embedding rows, cvt fp32->bf16, swizzled write (1 chunk/thread)
    int row = tid >> 4, c16 = tid & 15;
    const float* src;
    if (isW){ int q = qseq[tok0+row]; src = q_emb + (size_t)q*DKD + c16*8; }
    else    { int x = qseq[tok0+row] + NQ*cseq[tok0+row]; src = v_emb + (size_t)x*DKD + c16*8; }
    *(bh8*)(As + swz(row, c16, 256)) = cvt8(src);
  }
  if (isW){ // stage B = Mk (64 rows x 16 chunks), fp32 -> bf16
    #pragma unroll
    for (int m = 0; m < 2; ++m){
      int idx = tid + 512*m; int row = idx >> 4, c16 = idx & 15;
      *(bh8*)(Bs + swz(row, c16, 256)) = cvt8(Mk + (size_t)row*DKD + c16*8);
    }
  } else {  // stage B = [eW; aW] (256 rows x 16 chunks), fp32 -> bf16
    #pragma unroll
    for (int m = 0; m < 8; ++m){
      int idx = tid + 512*m; int row = idx >> 4, c16 = idx & 15;
      const float* src = (row < 128) ? (eW + (size_t)row*DKD) : (aW + (size_t)(row-128)*DKD);
      *(bh8*)(Bs + swz(row, c16, 256)) = cvt8(src + c16*8);
    }
  }
  __syncthreads();

  if (isW){
    const int m = wv & 1, n = wv >> 1;        // 8 waves -> 8 output tiles
    f32x4 acc = {0.f,0.f,0.f,0.f};
    #pragma unroll
    for (int kc = 0; kc < 4; ++kc){
      bh8 af = *(const bh8*)(As + swz(m*16 + (l&15), kc*4 + (l>>4), 256));
      bh8 bf = *(const bh8*)(Bs + swz(n*16 + (l&15), kc*4 + (l>>4), 256));
      acc = __builtin_amdgcn_mfma_f32_16x16x32_bf16(af, bf, acc, 0, 0, 0);
    }
    #pragma unroll
    for (int r = 0; r < 4; ++r){
      int tok = m*16 + (l>>4)*4 + r, out = n*16 + (l&15);
      Ls[tok*68 + out] = acc[r];
    }
    __syncthreads();
    // softmax: wave wv owns tokens 4wv..4wv+3; lane = slot
    #pragma unroll
    for (int i = 0; i < 4; ++i){
      int tok = wv*4 + i;
      float x = Ls[tok*68 + l];
      float mx = x;
      #pragma unroll
      for (int off = 32; off >= 1; off >>= 1) mx = fmaxf(mx, __shfl_xor(mx, off));
      float p = __expf(x - mx);
      float s = p;
      #pragma unroll
      for (int off = 32; off >= 1; off >>= 1) s += __shfl_xor(s, off);
      w_out[(size_t)(tok0+tok)*SLOTS + l] = p / s;
    }
  } else {
    const int m = wv & 1, nq = (wv >> 1) * 4; // 4 n-tiles per wave
    f32x4 acc[4] = {{0.f,0.f,0.f,0.f},{0.f,0.f,0.f,0.f},{0.f,0.f,0.f,0.f},{0.f,0.f,0.f,0.f}};
    #pragma unroll
    for (int kc = 0; kc < 4; ++kc){
      bh8 af = *(const bh8*)(As + swz(m*16 + (l&15), kc*4 + (l>>4), 256));
      #pragma unroll
      for (int j = 0; j < 4; ++j){
        bh8 bf = *(const bh8*)(Bs + swz((nq+j)*16 + (l&15), kc*4 + (l>>4), 256));
        acc[j] = __builtin_amdgcn_mfma_f32_16x16x32_bf16(af, bf, acc[j], 0, 0, 0);
      }
    }
    // transposed store: 4 acc values = 4 consecutive tokens at fixed d -> one float4
    // (4 | 200 so the quad never straddles a b boundary)
    #pragma unroll
    for (int j = 0; j < 4; ++j){
      int out = (nq+j)*16 + (l&15);
      bool is_e = (out < 128);
      int dd = out & 127;
      float bias = is_e ? eb[dd] : ab[dd];
      float4 sv;
      #pragma unroll
      for (int r = 0; r < 4; ++r){
        float xv = acc[j][r] + bias;
        ((float*)&sv)[r] = is_e ? sigmoidf_(xv) : tanhf_(xv);
      }
      int tg = tok0 + m*16 + (l>>4)*4;       // first of 4 consecutive tokens
      int bb = tg / SEQL, tl = tg - bb*SEQL;
      float* dst = (is_e ? eT : aT) + ((size_t)bb*DKD + dd)*SEQL + tl;
      *(float4*)dst = sv;
    }
  }
}

// ---------------- Scan: w in registers (TC=8 ping-pong), ea via transposed coalesced LDS,
// ---------------- bulk r-stores one chunk behind. Block = (b, 16 d); 512 blocks x 256 thr.
__device__ __forceinline__ float dpp_row_sum16(float x){
  float t;
  t = __builtin_bit_cast(float, __builtin_amdgcn_update_dpp(0, __builtin_bit_cast(int,x), 0x111, 0xf, 0xf, true)); x += t; // row_shr:1
  t = __builtin_bit_cast(float, __builtin_amdgcn_update_dpp(0, __builtin_bit_cast(int,x), 0x112, 0xf, 0xf, true)); x += t; // row_shr:2
  t = __builtin_bit_cast(float, __builtin_amdgcn_update_dpp(0, __builtin_bit_cast(int,x), 0x114, 0xf, 0xf, true)); x += t; // row_shr:4
  t = __builtin_bit_cast(float, __builtin_amdgcn_update_dpp(0, __builtin_bit_cast(int,x), 0x118, 0xf, 0xf, true)); x += t; // row_shr:8
  return x;  // lane 15 (mod 16) holds the 16-lane sum
}

#define TCH 8
#define NCH 25   // 25*8 = 200 exactly, no tail

__global__ __launch_bounds__(256) void scan_kernel(
    const float* __restrict__ Mv0,
    const float* __restrict__ w_in, const float* __restrict__ eT,
    const float* __restrict__ aT, u16* __restrict__ r16)
{
  __shared__ float eaS[2][2][16][8];   // [buf][e/a][chain d][t]  (2 KiB)
  __shared__ float rbuf[2][TCH][16];   // [buf][t][chain d]       (1 KiB)
  const int tid = threadIdx.x;
  const int b  = blockIdx.x >> 3;
  const int d0 = (blockIdx.x & 7) << 4;
  const int c  = tid >> 4;          // chain: d = d0 + c
  const int g  = tid & 15;          // slot quad: slots 4g..4g+3
  const int d  = d0 + c;
  const bool wlane = (g == 15);

  float mv0 = Mv0[(4*g+0)*DKD + d];
  float mv1 = Mv0[(4*g+1)*DKD + d];
  float mv2 = Mv0[(4*g+2)*DKD + d];
  float mv3 = Mv0[(4*g+3)*DKD + d];

  const float4* wsrc = (const float4*)(w_in + (size_t)b*SEQL*SLOTS);
  // ea staging: tid<128 -> e, else a; row sdd = (tid&127)>>3, t-offset sth = tid&7
  const int sdd = (tid & 127) >> 3, sth = tid & 7;
  const float* easrc = ((tid < 128) ? eT : aT) + ((size_t)b*DKD + d0 + sdd)*SEQL + sth;
  const int sarr = (tid < 128) ? 1 : 0;  // (index into eaS dim1: e->1? no: e->0) fixed below
  u16* rp = r16 + (size_t)b*SEQL*DKD + d0;

  float4 wA[TCH], wB[TCH];

  { // prologue: chunk 0 (w -> wA, ea -> LDS buf 0)
    #pragma unroll
    for (int i = 0; i < TCH; ++i) wA[i] = wsrc[i*16 + g];
    float ea0 = easrc[0];
    eaS[0][(tid < 128) ? 0 : 1][sdd][sth] = ea0;
    __syncthreads();
  }

  #define COMPUTE(P, WC)                                                  \
    _Pragma("unroll")                                                     \
    for (int u = 0; u < 2; ++u){                                          \
      float eq[4], aq[4];                                                 \
      *(float4*)eq = *(const float4*)&eaS[P][0][c][u*4];                  \
      *(float4*)aq = *(const float4*)&eaS[P][1][c][u*4];                  \
      _Pragma("unroll")                                                   \
      for (int v = 0; v < 4; ++v){                                        \
        const int tt = u*4 + v;                                           \
        float4 wq = WC[tt];                                               \
        float r = wq.x*mv0; r = fmaf(wq.y, mv1, r);                       \
        r = fmaf(wq.z, mv2, r); r = fmaf(wq.w, mv3, r);                   \
        r = dpp_row_sum16(r);                                             \
        if (wlane) rbuf[P][tt][c] = r;                                    \
        const float ev = eq[v], av = aq[v];                               \
        mv0 = fmaf(wq.x, fmaf(-mv0, ev, av), mv0);                        \
        mv1 = fmaf(wq.y, fmaf(-mv1, ev, av), mv1);                        \
        mv2 = fmaf(wq.z, fmaf(-mv2, ev, av), mv2);                        \
        mv3 = fmaf(wq.w, fmaf(-mv3, ev, av), mv3);                        \
      }                                                                   \
    }

  #define STORER(CK, P)                                                  \
    if (tid < 64){                                                       \
      int t = tid >> 3, dp = tid & 7;                                    \
      float2 rv = *(const float2*)&rbuf[P][t][dp*2];                     \
      u32 pk = (u32)f2b(rv.x) | ((u32)f2b(rv.y) << 16);                  \
      *(u32*)(rp + (size_t)((CK)*TCH + t)*DKD + dp*2) = pk;              \
    }

  #define PHASE(CK, P, WC, WN)                                           \
    {                                                                    \
      if ((CK) > 0) STORER((CK)-1, (P)^1);                               \
      const int T0n = ((CK)+1)*TCH;                                      \
      _Pragma("unroll")                                                  \
      for (int i = 0; i < TCH; ++i) WN[i] = wsrc[(T0n+i)*16 + g];        \
      float ean = easrc[T0n];                                            \
      COMPUTE(P, WC)                                                     \
      eaS[(P)^1][(tid < 128) ? 0 : 1][sdd][sth] = ean;                   \
      __syncthreads();                                                   \
    }

  for (int ck = 0; ck < 24; ck += 2){
    PHASE(ck,   0, wA, wB)
    PHASE(ck+1, 1, wB, wA)
  }
  // final chunk 24 (parity 0, data in wA / eaS[0]); no prefetch
  STORER(23, 1);
  COMPUTE(0, wA)
  __syncthreads();
  STORER(24, 0);

  #undef COMPUTE
  #undef STORER
  #undef PHASE
  (void)sarr;
}

// ---------------- P3: f = tanh([read|k] fW^T + fb); out = sigmoid(f pW + pb) ----------------
// 512 thr = 8 waves; 32 tok/block; A = [r16 | k] bf16 (K=256), B = fW cvt'd. LDS 80 KiB.
__global__ __launch_bounds__(512) void p3_kernel(
    const int* __restrict__ qseq, const float* __restrict__ q_emb,
    const u16* __restrict__ r16, const float* __restrict__ fW,
    const float* __restrict__ fb, const float* __restrict__ pW,
    const float* __restrict__ pb, float* __restrict__ out)
{
  __shared__ __align__(16) char smem[81920];
  char* As = smem;            // [32 rows][512B]
  char* Bs = smem + 16384;    // [128 rows][512B]

  const int tid = threadIdx.x;
  const int l = tid & 63, wv = tid >> 6;
  const int tok0 = blockIdx.x * 32;

  #pragma unroll
  for (int m = 0; m < 2; ++m){   // stage A: 1024 chunks (rows 512B = 32 chunks)
    int idx = tid + 512*m; int row = idx >> 5, c16 = idx & 31;
    bh8 v;
    if (c16 < 16){
      v = *(const bh8*)(r16 + (size_t)(tok0+row)*DKD + c16*8);
    } else {
      int q = qseq[tok0+row];
      v = cvt8(q_emb + (size_t)q*DKD + (c16-16)*8);
    }
    *(bh8*)(As + swz(row, c16, 512)) = v;
  }
  #pragma unroll
  for (int m = 0; m < 8; ++m){   // stage B: 4096 chunks, fp32 fW -> bf16
    int idx = tid + 512*m; int row = idx >> 5, c16 = idx & 31;
    *(bh8*)(Bs + swz(row, c16, 512)) = cvt8(fW + (size_t)row*256 + c16*8);
  }
  __syncthreads();

  const int m = wv & 1, np = (wv >> 1) * 2;   // 2 n-tiles per wave
  f32x4 acc[2] = {{0.f,0.f,0.f,0.f},{0.f,0.f,0.f,0.f}};
  #pragma unroll
  for (int kc = 0; kc < 8; ++kc){
    bh8 af = *(const bh8*)(As + swz(m*16 + (l&15), kc*4 + (l>>4), 512));
    #pragma unroll
    for (int j = 0; j < 2; ++j){
      bh8 bf = *(const bh8*)(Bs + swz((np+j)*16 + (l&15), kc*4 + (l>>4), 512));
      acc[j] = __builtin_amdgcn_mfma_f32_16x16x32_bf16(af, bf, acc[j], 0, 0, 0);
    }
  }
  // per-lane partial p over this wave's 32 out-columns
  float pp[4] = {0.f,0.f,0.f,0.f};
  #pragma unroll
  for (int j = 0; j < 2; ++j){
    int o = (np+j)*16 + (l&15);
    float bias = fb[o], pw = pW[o];
    #pragma unroll
    for (int r = 0; r < 4; ++r){
      float f = tanhf_(acc[j][r] + bias);
      pp[r] = fmaf(f, pw, pp[r]);
    }
  }
  #pragma unroll
  for (int r = 0; r < 4; ++r){   // reduce across the 16 out-lanes
    pp[r] += __shfl_xor(pp[r], 1);
    pp[r] += __shfl_xor(pp[r], 2);
    pp[r] += __shfl_xor(pp[r], 4);
    pp[r] += __shfl_xor(pp[r], 8);
  }
  __syncthreads();
  float* pbuf = (float*)smem;    // overlay on As (done with it): [8 waves][32 tok]
  if ((l & 15) == 0){
    #pragma unroll
    for (int r = 0; r < 4; ++r){
      int tok = m*16 + (l>>4)*4 + r;
      pbuf[wv*32 + tok] = pp[r];
    }
  }
  __syncthreads();
  if (tid < 32){
    int mm = tid >> 4;   // token's m-half -> waves with wv&1 == mm
    float s = pbuf[(mm+0)*32 + tid] + pbuf[(mm+2)*32 + tid]
            + pbuf[(mm+4)*32 + tid] + pbuf[(mm+6)*32 + tid];
    out[tok0 + tid] = sigmoidf_(s + pb[0]);
  }
}

extern "C" void kernel_launch(void* const* d_in, const int* in_sizes, int n_in,
                              void* d_out, int out_size, void* d_ws, size_t ws_size,
                              hipStream_t stream) {
  const int*   qseq  = (const int*)d_in[0];
  const int*   cseq  = (const int*)d_in[1];
  const float* q_emb = (const float*)d_in[2];
  const float* v_emb = (const float*)d_in[3];
  const float* Mk    = (const float*)d_in[4];
  const float* Mv0   = (const float*)d_in[5];
  const float* eW    = (const float*)d_in[6];
  const float* eb    = (const float*)d_in[7];
  const float* aW    = (const float*)d_in[8];
  const float* ab    = (const float*)d_in[9];
  const float* fW    = (const float*)d_in[10];
  const float* fb    = (const float*)d_in[11];
  const float* pW    = (const float*)d_in[12];
  const float* pb    = (const float*)d_in[13];

  char* ws = (char*)d_ws;
  float* w_buf = (float*)ws;                                   // 12800*64*4   = 3,276,800
  float* eT    = (float*)(ws + 3276800);                       // 64*128*200*4 = 6,553,600
  float* aT    = (float*)(ws + 9830400);                       // 6,553,600
  u16*   r16   = (u16*)  (ws + 16384000);                      // 12800*128*2  = 3,276,800 (end ~19.7 MB)
  float* outp  = (float*)d_out;

  hipLaunchKernelGGL(wea_kernel, dim3(800), dim3(512), 0, stream,
                     qseq, cseq, q_emb, v_emb, Mk, eW, aW, eb, ab,
                     w_buf, eT, aT);
  hipLaunchKernelGGL(scan_kernel, dim3(512), dim3(256), 0, stream,
                     Mv0, w_buf, eT, aT, r16);
  hipLaunchKernelGGL(p3_kernel, dim3(NTOK/32), dim3(512), 0, stream,
                     qseq, q_emb, r16, fW, fb, pW, pb, outp);
}